// Round 14
// baseline (782.418 us; speedup 1.0000x reference)
//
#include <hip/hip_runtime.h>
#include <stdint.h>

typedef int int32x4 __attribute__((ext_vector_type(4)));

constexpr int K_DIM = 4096;   // D_IN
constexpr int N_DIM = 4096;   // D_OUT
constexpr float QMAXF = 127.0f;

// ---------------------------------------------------------------------------
// Kernel 1: per-token absmax quant -> FRAGMENT-MAJOR q_t (r13-exact, passed).
// ---------------------------------------------------------------------------
__global__ __launch_bounds__(256) void quant_t(const float* __restrict__ x,
                                               int8_t* __restrict__ qt,
                                               float* __restrict__ scales) {
    __shared__ int8_t lq[16][4112];
    const int b = blockIdx.x;          // panel
    const int tid = threadIdx.x;
    const int row16 = tid >> 4;        // 0..15
    const int j = tid & 15;
    const size_t rbase = ((size_t)b * 16 + row16) * K_DIM;
    const float4* xr = reinterpret_cast<const float4*>(x + rbase);

    float m = 0.0f;
#pragma unroll 4
    for (int i = 0; i < 16; ++i) {
        const int c = j + 16 * i;
#pragma unroll
        for (int s = 0; s < 4; ++s) {
            float4 v = xr[c * 4 + s];
            m = fmaxf(m, fmaxf(fmaxf(fabsf(v.x), fabsf(v.y)),
                               fmaxf(fabsf(v.z), fabsf(v.w))));
        }
    }
#pragma unroll
    for (int off = 8; off > 0; off >>= 1) m = fmaxf(m, __shfl_xor(m, off));
    const float scale = fmaxf(m * (1.0f / 127.0f), 1e-8f);
    if (j == 0) scales[b * 16 + row16] = scale;
    const float inv = 1.0f / scale;

#pragma unroll 4
    for (int i = 0; i < 16; ++i) {
        const int c = j + 16 * i;
        int w[4];
#pragma unroll
        for (int s = 0; s < 4; ++s) {
            float4 v = xr[c * 4 + s];
            int b0 = ((int)fminf(QMAXF, fmaxf(-QMAXF, rintf(v.x * inv)))) & 255;
            int b1 = ((int)fminf(QMAXF, fmaxf(-QMAXF, rintf(v.y * inv)))) & 255;
            int b2 = ((int)fminf(QMAXF, fmaxf(-QMAXF, rintf(v.z * inv)))) & 255;
            int b3 = ((int)fminf(QMAXF, fmaxf(-QMAXF, rintf(v.w * inv)))) & 255;
            w[s] = b0 | (b1 << 8) | (b2 << 16) | (b3 << 24);
        }
        *reinterpret_cast<int32x4*>(&lq[row16][c * 16]) = (int32x4){w[0], w[1], w[2], w[3]};
    }
    __syncthreads();

    int8_t* outp = qt + (size_t)b * 65536;
#pragma unroll
    for (int i = 0; i < 16; ++i) {
        const int u = tid + 256 * i;
        int32x4 v = *reinterpret_cast<const int32x4*>(&lq[u & 15][(u >> 4) * 16]);
        *reinterpret_cast<int32x4*>(outp + (size_t)u * 16) = v;
    }
}

// ---------------------------------------------------------------------------
// Kernel 2: pack int32 weight buffer -> int8
// ---------------------------------------------------------------------------
__global__ __launch_bounds__(256) void pack_w(const int* __restrict__ w,
                                              int8_t* __restrict__ w8) {
    const int idx = blockIdx.x * 256 + threadIdx.x;
    const int4 v = reinterpret_cast<const int4*>(w)[idx];
    int packed = (v.x & 255) | ((v.y & 255) << 8) | ((v.z & 255) << 16) | ((v.w & 255) << 24);
    reinterpret_cast<int*>(w8)[idx] = packed;
}

// ---------------------------------------------------------------------------
// Kernel 3: flatmm-v4 — r13 structure at 4 WAVES/SIMD (the TLP experiment).
// 256x256 tile, BKB=128, 8 waves (4M x 2N, wave tile 64x128), 16x16x64 MFMA.
//  - __launch_bounds__(512, 4): VGPR cap 128 (r13 measured 116) -> 2 blocks/CU
//    = 16 waves/CU = 4 waves/SIMD, two independent barrier domains.
//  - B ring-2 dbuf (2 x 32KB = 64 KB/block; 128 KB/CU total).
//  - A: global->VGPR from fragment-major q_t, loaded at tile TOP for the
//    CURRENT tile (contiguous 1KB/wave frags, L1/L2-resident; 4-wave TLP
//    hides the latency). Issued BEFORE the B GLLs, so the compiler's
//    auto-wait for af (vmcnt(4), in-order retire) leaves B(t+1) in flight.
//  - GLL B(t+1) issued after A loads; end-of-tile vmcnt(0)+barrier (B(t+1)
//    was issued ~a full tile earlier -> landed; drain is cheap, and the
//    other block on the CU covers it).
//  - WAR: GLL B(t+1) -> slot (t+1)&1, last read in tile t-1, finished
//    before tile-t top barrier. Safe.
//  - bf ping-pong reads + lgkmcnt(2) gates (r12/r13-exact, 0 conflicts).
// ---------------------------------------------------------------------------
constexpr int BM = 256, BN = 256, BKB = 128;
constexpr int NT = K_DIM / BKB;    // 32 K-tiles
constexpr int BSLOT = 32768;       // B slot bytes

#define GLL(src, dst)                                                          \
    __builtin_amdgcn_global_load_lds(                                          \
        (const __attribute__((address_space(1))) unsigned int*)(src),          \
        (__attribute__((address_space(3))) unsigned int*)(dst), 16, 0, 0)

#define MFMA_I8(a, b, c) __builtin_amdgcn_mfma_i32_16x16x64_i8((a), (b), (c), 0, 0, 0)

__global__ __launch_bounds__(512, 4) void w8a8_flat(
        const int8_t* __restrict__ QT, const int8_t* __restrict__ B,
        const float* __restrict__ asc, const float* __restrict__ wsc,
        float* __restrict__ C, int M) {
    extern __shared__ int8_t lds[];   // 64 KB B dbuf

    const int tid  = threadIdx.x;
    const int lane = tid & 63;
    const int wave = tid >> 6;

    // XCD-aware bijective swizzle (nwg = 512, divisible by 8)
    const int nwg = gridDim.x;
    const int bid = blockIdx.x;
    const int swz = (bid & 7) * (nwg >> 3) + (bid >> 3);
    const int NB  = N_DIM / BN;               // 16
    const int brow = (swz / NB) * BM;
    const int bcol = (swz % NB) * BN;

    const int wm = wave & 3;                  // 0..3 (64-row quarter)
    const int wn = wave >> 2;                 // 0..1 (128-col half)
    const int l15 = lane & 15;
    const int ls  = lane >> 4;

    // ---- A fragment-major base: + ((wm*4+mi)*64 + t*2 + kh)*1024 ----
    const int8_t* qa = QT + (size_t)(brow >> 4) * 65536 + lane * 16;

    // ---- B staging (r6-exact, 0 conflicts) ----
    const int rowst = tid >> 3;                           // 0..63
    const int gsl   = ((tid & 7) ^ (rowst & 7)) * 16;     // swizzled granule
    const int8_t* gB = B + (size_t)(bcol + rowst) * K_DIM + gsl;
    const size_t chB = (size_t)64 * K_DIM;                // +64 rows
    const int segb = wave * 1024;                         // wave-uniform LDS base

    // ---- B compute-side swizzled offset (r6-exact) ----
    const int boff = (wn * 128 + l15) * BKB + ((ls ^ (l15 & 7)) * 16);
    // + ni*2048 ; kh=1 -> ^64 ; + slot*BSLOT

    int32x4 acc[4][8];
#pragma unroll
    for (int i = 0; i < 4; ++i)
#pragma unroll
        for (int j = 0; j < 8; ++j) acc[i][j] = (int32x4){0, 0, 0, 0};

    // ---- prologue: stage B(0) ----
#pragma unroll
    for (int c = 0; c < 4; ++c) GLL(gB + c * chB, lds + c * 8192 + segb);
    asm volatile("s_waitcnt vmcnt(0)" ::: "memory");
    __builtin_amdgcn_s_barrier();

    int32x4 af[8];

    for (int t = 0; t < NT; ++t) {
        const int8_t* Bb = lds + (t & 1) * BSLOT;
        const bool pf = (t + 1 < NT);

        // A frags of CURRENT tile (issued first: oldest in vmcnt queue)
#pragma unroll
        for (int mi = 0; mi < 4; ++mi) {
            const int8_t* ap = qa + ((((wm * 4 + mi) * 64) + t * 2) << 10);
            af[2 * mi]     = *(const int32x4*)(ap);
            af[2 * mi + 1] = *(const int32x4*)(ap + 1024);
        }
        // GLL B(t+1) (issued after A: stays in flight past the A-waits)
        if (pf) {
            int8_t* dst = lds + ((t + 1) & 1) * BSLOT;
#pragma unroll
            for (int c = 0; c < 4; ++c)
                GLL(gB + (t + 1) * 128 + c * chB, dst + c * 8192 + segb);
        }

        int32x4 bf[2][2];
        bf[0][0] = *(const int32x4*)(Bb + boff);
        bf[0][1] = *(const int32x4*)(Bb + (boff ^ 64));
#pragma unroll
        for (int ni = 0; ni < 8; ++ni) {
            const int cur = ni & 1, nxt = cur ^ 1;
            if (ni < 7) {
                const int o = boff + (ni + 1) * 2048;
                bf[nxt][0] = *(const int32x4*)(Bb + o);
                bf[nxt][1] = *(const int32x4*)(Bb + (o ^ 64));
                asm volatile("s_waitcnt lgkmcnt(2)" ::: "memory");
            } else {
                asm volatile("s_waitcnt lgkmcnt(0)" ::: "memory");
            }
            __builtin_amdgcn_sched_barrier(0);
            __builtin_amdgcn_s_setprio(1);
#pragma unroll
            for (int mi = 0; mi < 4; ++mi) {
                acc[mi][ni] = MFMA_I8(af[2 * mi], bf[cur][0], acc[mi][ni]);
                acc[mi][ni] = MFMA_I8(af[2 * mi + 1], bf[cur][1], acc[mi][ni]);
            }
            __builtin_amdgcn_s_setprio(0);
        }

        // B(t+1) must be visible before next tile's reads
        asm volatile("s_waitcnt vmcnt(0)" ::: "memory");
        __builtin_amdgcn_sched_barrier(0);
        __builtin_amdgcn_s_barrier();
    }

    // ---- epilogue (r13-exact): col=lane&15, row=(lane>>4)*4+reg ----
    const int c0  = lane & 15;
    const int rr0 = (lane >> 4) * 4;
#pragma unroll
    for (int ni = 0; ni < 8; ++ni) {
        const int col = bcol + wn * 128 + ni * 16 + c0;
        const float ws = wsc[col];
#pragma unroll
        for (int mi = 0; mi < 4; ++mi) {
            const int rowb = brow + wm * 64 + mi * 16 + rr0;
#pragma unroll
            for (int r = 0; r < 4; ++r) {
                const int row = rowb + r;
                float o = (float)acc[mi][ni][r] * asc[row] * ws;
                o = (float)(_Float16)o;   // emulate reference's fp16 cast
                C[(size_t)row * N_DIM + col] = o;
            }
        }
    }
}

// ---------------------------------------------------------------------------
extern "C" void kernel_launch(void* const* d_in, const int* in_sizes, int n_in,
                              void* d_out, int out_size, void* d_ws, size_t ws_size,
                              hipStream_t stream) {
    const float* x   = (const float*)d_in[0];   // [M][K], fp16-valued f32
    const int*   w   = (const int*)d_in[1];     // [N][K] int32 (int8-valued)
    const float* wsc = (const float*)d_in[2];   // [N]
    float* out = (float*)d_out;                 // [M][N] (fp16-valued f32)

    const int K = K_DIM;
    const int M = in_sizes[0] / K;              // 8192
    const int N = N_DIM;

    int8_t* qt  = (int8_t*)d_ws;                               // M*K  = 32 MB
    int8_t* w8  = (int8_t*)d_ws + (size_t)M * K;               // N*K  = 16 MB
    float*  asc = (float*)((char*)d_ws + (size_t)M * K + (size_t)N * K);

    quant_t<<<M / 16, 256, 0, stream>>>(x, qt, asc);
    pack_w<<<(N * (K / 4)) / 256, 256, 0, stream>>>(w, w8);
    const int grid = (M / BM) * (N / BN);       // 512
    w8a8_flat<<<grid, 512, 65536, stream>>>(qt, w8, asc, wsc, out, M);
}